// Round 8
// baseline (28.804 us; speedup 1.0000x reference)
//
#include <hip/hip_runtime.h>
#include <math.h>

typedef _Float16 f16;
typedef f16 f16x8 __attribute__((ext_vector_type(8)));
typedef float f32x16 __attribute__((ext_vector_type(16)));

static constexpr int Bn = 16;
static constexpr int Kn = 4096;
static constexpr int NPTS = Bn * Kn;    // 65536
static constexpr int MGRID = 512;       // qg8(16) x b(16) x dir(2)
static constexpr int NPSUM = 1024;      // psum keeps the OLD 1024-slot layout
static constexpr float WBIG = 49152.0f; // exact in fp16
static constexpr float QMIN0 = 3e37f;

static constexpr size_t FRAG_BYTES = (size_t)NPTS * 32;

// 16 K-slot values (13 used) for v_mfma_f32_32x32x16_f16:
// d2[r][q] = sum_k A[r][k]*B[k][q]
//  k0..8 : error-compensated -2*dot (hh, hl, lh per coord)
//  k9,10 : ref ||.||^2 (hi,lo) * 1 ;  k11,12: 1 * query ||.||^2 (hi,lo)
// invalid as ref: w=+WBIG (never wins min); invalid as query: w=-WBIG
// (min << -1e4 -> dropped at the sqrt stage).
__device__ inline void mk_slots(float x, float y, float z, bool valid,
                                f16 A[16], f16 B[16]) {
    float w = fmaf(x, x, fmaf(y, y, z * z));
    f16 xh = (f16)x, yh = (f16)y, zh = (f16)z;
    f16 xl = (f16)(x - (float)xh), yl = (f16)(y - (float)yh), zl = (f16)(z - (float)zh);
    f16 m2xh = (f16)(-2.0f * (float)xh), m2xl = (f16)(-2.0f * (float)xl);
    f16 m2yh = (f16)(-2.0f * (float)yh), m2yl = (f16)(-2.0f * (float)yl);
    f16 m2zh = (f16)(-2.0f * (float)zh), m2zl = (f16)(-2.0f * (float)zl);
    f16 one = (f16)1.0f, zero = (f16)0.0f;
    f16 whA, wlA, whB, wlB;
    if (valid) {
        f16 wh = (f16)w; f16 wl = (f16)(w - (float)wh);
        whA = wh; wlA = wl; whB = wh; wlB = wl;
    } else {
        whA = (f16)WBIG;   wlA = zero;
        whB = (f16)(-WBIG); wlB = zero;
    }
    A[0] = m2xh; A[1] = m2xh; A[2] = m2xl;
    A[3] = m2yh; A[4] = m2yh; A[5] = m2yl;
    A[6] = m2zh; A[7] = m2zh; A[8] = m2zl;
    A[9] = whA; A[10] = wlA; A[11] = one; A[12] = one;
    A[13] = zero; A[14] = zero; A[15] = zero;
    B[0] = xh; B[1] = xl; B[2] = xh;
    B[3] = yh; B[4] = yl; B[5] = yh;
    B[6] = zh; B[7] = zl; B[8] = zh;
    B[9] = one; B[10] = one; B[11] = whB; B[12] = wlB;
    B[13] = zero; B[14] = zero; B[15] = zero;
}

// 32x32x16 tile = 64 entries of f16x8. Lane l -> row/col = l&31, k-group
// g = l>>5. Entry index: g*32 + r. A-slot j and B-slot j at the same (g, i)
// position -> products pair under any shared k-bijection.
// Also writes the opaque 64-B zero block for the mfma kernel's C operand.
__global__ __launch_bounds__(256) void prep_kernel(
        const float* __restrict__ pred, const float* __restrict__ target,
        const int* __restrict__ mask,
        f16x8* __restrict__ predA, f16x8* __restrict__ predB,
        f16x8* __restrict__ tgtA, f16x8* __restrict__ tgtB,
        unsigned int* __restrict__ cnt4, float* __restrict__ czero) {
    int idx = blockIdx.x * 256 + threadIdx.x;
    if (idx < 16) czero[idx] = 0.0f;
    bool valid = mask[idx] != 0;

    float px = pred[idx * 3 + 0], py = pred[idx * 3 + 1], pz = pred[idx * 3 + 2];
    float tx = target[idx * 3 + 0], ty = target[idx * 3 + 1], tz = target[idx * 3 + 2];
    if (!valid) { px = py = pz = 0.0f; tx = ty = tz = 0.0f; }

    f16 PA[16], PB[16], TA[16], TB[16];
    mk_slots(px, py, pz, valid, PA, PB);
    mk_slots(tx, ty, tz, valid, TA, TB);

    int b = idx >> 12, kk = idx & 4095;
    int rt = kk >> 5, r = kk & 31;
    size_t base = ((size_t)(b * 128 + rt)) * 64;

    #pragma unroll
    for (int g = 0; g < 2; ++g) {
        int o = g * 8;
        predA[base + g * 32 + r] = (f16x8){PA[o+0],PA[o+1],PA[o+2],PA[o+3],PA[o+4],PA[o+5],PA[o+6],PA[o+7]};
        predB[base + g * 32 + r] = (f16x8){PB[o+0],PB[o+1],PB[o+2],PB[o+3],PB[o+4],PB[o+5],PB[o+6],PB[o+7]};
        tgtA[base + g * 32 + r]  = (f16x8){TA[o+0],TA[o+1],TA[o+2],TA[o+3],TA[o+4],TA[o+5],TA[o+6],TA[o+7]};
        tgtB[base + g * 32 + r]  = (f16x8){TB[o+0],TB[o+1],TB[o+2],TB[o+3],TB[o+4],TB[o+5],TB[o+6],TB[o+7]};
    }

    unsigned long long mb = __ballot(valid);
    if ((threadIdx.x & 63) == 0)
        cnt4[idx >> 6] = (unsigned int)__popcll(mb);
}

// Round-8: qt=8 / 512 blocks (R7's traffic: 67 MB) but 512-thread blocks =
// 8 waves, each covering 16 ref-tiles (stride 8). 2 blocks/CU x 8 waves =
// 4 waves/SIMD — 2x R7's TLP at IDENTICAL per-block A-traffic. R2's PMC
// showed MFMA-busy time == the 6.9 us pipe floor while the kernel idles
// ~70%: the frugal-register codegen serializes mfma -> result-wait -> min3
// (~60 cyc chain per 32-cyc MFMA), so idle gaps need OTHER waves to fill.
// Clamp arithmetic (R4/R6 lesson): __launch_bounds__(512,4) -> k = 4*4/8 =
// 2 blocks/CU = exactly the grid; VGPR cap 128 >> the ~70-100 the qt=8
// loop needs -> no clamp-spill.
// Bitwise (R4-validated pattern, absmax 0.0): min over the same 128
// ref-tiles under an 8-way partition is exact; waves 4-7 contribute real
// minima to comb but exact +0.0 to the contrib sums (tid>=256 -> c=0);
// adding +0.0 is exact; psum j0/j1 layout and final_kernel unchanged.
__global__ __launch_bounds__(512, 4) void chamfer_mfma_kernel(
        const f16x8* __restrict__ predA, const f16x8* __restrict__ predB,
        const f16x8* __restrict__ tgtA, const f16x8* __restrict__ tgtB,
        const float* __restrict__ czero, float* __restrict__ psum) {
    int bid = blockIdx.x;
    int lin = (bid & 7) * 64 + (bid >> 3);    // XCD-contiguous logical id
    int qg8 = lin & 15; lin >>= 4;            // qg8(16) fastest, b(16), dir(2)
    int b   = lin & 15; lin >>= 4;
    int dir = lin;                            // 0: queries=pred, refs=target
    int j0 = dir * 512 + b * 32 + qg8 * 2;    // old logical psum slots
    int j1 = j0 + 1;

    const f16x8* __restrict__ Apack = dir ? predA : tgtA;  // refs
    const f16x8* __restrict__ Bpack = dir ? tgtB  : predB; // queries

    int tid = threadIdx.x;
    int w = tid >> 6, l = tid & 63;           // w in 0..7

    __shared__ float comb[8][8][64];

    f16x8 bq[8];
    #pragma unroll
    for (int qt = 0; qt < 8; ++qt)
        bq[qt] = Bpack[((size_t)(b * 128 + qg8 * 8 + qt)) * 64 + l];

    // opaque zero C-operand (value IS zero; provenance hidden from compiler)
    f32x16 cz = *(const f32x16*)czero;

    float qA[8], qB[8];
    #pragma unroll
    for (int qt = 0; qt < 8; ++qt) { qA[qt] = QMIN0; qB[qt] = QMIN0; }

    // wave w covers ref-tiles rt = w + 8t', t' = 0..15 (ascending)
    size_t abase = ((size_t)(b * 128)) * 64 + (size_t)w * 64 + l;
    #pragma unroll 4
    for (int t = 0; t < 16; ++t) {
        f16x8 a = Apack[abase + (size_t)t * 512];
        #pragma unroll
        for (int qt = 0; qt < 8; ++qt) {
            f32x16 d = __builtin_amdgcn_mfma_f32_32x32x16_f16(a, bq[qt], cz, 0, 0, 0);
            #pragma unroll
            for (int i = 0; i < 4; ++i) {
                qA[qt] = fminf(fminf(qA[qt], d[4 * i + 0]), d[4 * i + 1]);  // -> v_min3
                qB[qt] = fminf(fminf(qB[qt], d[4 * i + 2]), d[4 * i + 3]);  // -> v_min3
            }
        }
    }

    #pragma unroll
    for (int qt = 0; qt < 8; ++qt) comb[w][qt][l] = fminf(qA[qt], qB[qt]);
    __syncthreads();

    // Two independent reductions, each the EXACT old-block computation
    // (min over the same 128-tile set; order-free since min is exact).
    float c0 = 0.0f, c1 = 0.0f;
    if (tid < 128) {
        int qt = tid >> 5, c = tid & 31;
        float m0 = QMIN0, m1 = QMIN0;
        #pragma unroll
        for (int ww = 0; ww < 8; ++ww)
            #pragma unroll
            for (int h = 0; h < 2; ++h) {
                m0 = fminf(m0, comb[ww][qt][h * 32 + c]);
                m1 = fminf(m1, comb[ww][qt + 4][h * 32 + c]);
            }
        // m < -1e4 marks an invalid query (w_q = -WBIG); contributes 0
        c0 = (m0 < -1e4f) ? 0.0f : sqrtf(fmaxf(m0, 1e-12f));
        c1 = (m1 < -1e4f) ? 0.0f : sqrtf(fmaxf(m1, 1e-12f));
    }
    for (int off = 32; off; off >>= 1) {
        c0 += __shfl_down(c0, off, 64);
        c1 += __shfl_down(c1, off, 64);
    }
    __shared__ float ps0[8], ps1[8];
    if ((tid & 63) == 0) { ps0[tid >> 6] = c0; ps1[tid >> 6] = c1; }
    __syncthreads();
    if (tid == 0) {
        float s0 = 0.0f, s1 = 0.0f;
        #pragma unroll
        for (int ww = 0; ww < 8; ++ww) {      // ps*[4..7] == +0.0, exact
            s0 += ps0[ww];
            s1 += ps1[ww];
        }
        psum[j0] = s0;
        psum[j1] = s1;
    }
}

__global__ __launch_bounds__(256) void final_kernel(
        const unsigned int* __restrict__ cnt4, const float* __restrict__ psum,
        float* __restrict__ out) {
    int t = threadIdx.x;
    unsigned int c = 0;
    float s = 0.0f;
    #pragma unroll
    for (int i = 0; i < 4; ++i) {
        c += cnt4[t + 256 * i];
        s += psum[t + 256 * i];
    }
    for (int off = 32; off; off >>= 1) {
        c += __shfl_down(c, off, 64);
        s += __shfl_down(s, off, 64);
    }
    __shared__ unsigned int cs[4];
    __shared__ float ss[4];
    if ((t & 63) == 0) { cs[t >> 6] = c; ss[t >> 6] = s; }
    __syncthreads();
    if (t == 0) {
        unsigned int C = cs[0] + cs[1] + cs[2] + cs[3];
        float S = ss[0] + ss[1] + ss[2] + ss[3];
        out[0] = S * 0.5f / ((float)C + 1e-8f);
    }
}

extern "C" void kernel_launch(void* const* d_in, const int* in_sizes, int n_in,
                              void* d_out, int out_size, void* d_ws, size_t ws_size,
                              hipStream_t stream) {
    const float* pred = (const float*)d_in[0];
    const float* target = (const float*)d_in[1];
    const int* mask = (const int*)d_in[2];
    float* out = (float*)d_out;

    // ws: [predA 2M | predB 2M | tgtA 2M | tgtB 2M | psum 4K | cnt4 4K | czero 64B]
    char* ws = (char*)d_ws;
    size_t off = 0;
    f16x8* predA = (f16x8*)(ws + off); off += FRAG_BYTES;
    f16x8* predB = (f16x8*)(ws + off); off += FRAG_BYTES;
    f16x8* tgtA  = (f16x8*)(ws + off); off += FRAG_BYTES;
    f16x8* tgtB  = (f16x8*)(ws + off); off += FRAG_BYTES;
    float* psum = (float*)(ws + off); off += NPSUM * sizeof(float);
    unsigned int* cnt4 = (unsigned int*)(ws + off); off += 1024 * sizeof(unsigned int);
    float* czero = (float*)(ws + off);

    prep_kernel<<<NPTS / 256, 256, 0, stream>>>(
        pred, target, mask, predA, predB, tgtA, tgtB, cnt4, czero);
    chamfer_mfma_kernel<<<MGRID, 512, 0, stream>>>(
        predA, predB, tgtA, tgtB, czero, psum);
    final_kernel<<<1, 256, 0, stream>>>(cnt4, psum, out);
}

// Round 9
// 28.491 us; speedup vs baseline: 1.0110x; 1.0110x over previous
//
#include <hip/hip_runtime.h>
#include <math.h>

typedef _Float16 f16;
typedef f16 f16x8 __attribute__((ext_vector_type(8)));
typedef float f32x16 __attribute__((ext_vector_type(16)));

static constexpr int Bn = 16;
static constexpr int Kn = 4096;
static constexpr int NPTS = Bn * Kn;    // 65536
static constexpr int MGRID = 512;       // qg8(16) x b(16) x dir(2)
static constexpr int NPSUM = 1024;      // psum keeps the OLD 1024-slot layout
static constexpr float WBIG = 49152.0f; // exact in fp16
static constexpr float QMIN0 = 3e37f;

static constexpr size_t FRAG_BYTES = (size_t)NPTS * 32;

// 16 K-slot values (13 used) for v_mfma_f32_32x32x16_f16:
// d2[r][q] = sum_k A[r][k]*B[k][q]
//  k0..8 : error-compensated -2*dot (hh, hl, lh per coord)
//  k9,10 : ref ||.||^2 (hi,lo) * 1 ;  k11,12: 1 * query ||.||^2 (hi,lo)
// invalid as ref: w=+WBIG (never wins min); invalid as query: w=-WBIG
// (min << -1e4 -> dropped at the sqrt stage).
__device__ inline void mk_slots(float x, float y, float z, bool valid,
                                f16 A[16], f16 B[16]) {
    float w = fmaf(x, x, fmaf(y, y, z * z));
    f16 xh = (f16)x, yh = (f16)y, zh = (f16)z;
    f16 xl = (f16)(x - (float)xh), yl = (f16)(y - (float)yh), zl = (f16)(z - (float)zh);
    f16 m2xh = (f16)(-2.0f * (float)xh), m2xl = (f16)(-2.0f * (float)xl);
    f16 m2yh = (f16)(-2.0f * (float)yh), m2yl = (f16)(-2.0f * (float)yl);
    f16 m2zh = (f16)(-2.0f * (float)zh), m2zl = (f16)(-2.0f * (float)zl);
    f16 one = (f16)1.0f, zero = (f16)0.0f;
    f16 whA, wlA, whB, wlB;
    if (valid) {
        f16 wh = (f16)w; f16 wl = (f16)(w - (float)wh);
        whA = wh; wlA = wl; whB = wh; wlB = wl;
    } else {
        whA = (f16)WBIG;   wlA = zero;
        whB = (f16)(-WBIG); wlB = zero;
    }
    A[0] = m2xh; A[1] = m2xh; A[2] = m2xl;
    A[3] = m2yh; A[4] = m2yh; A[5] = m2yl;
    A[6] = m2zh; A[7] = m2zh; A[8] = m2zl;
    A[9] = whA; A[10] = wlA; A[11] = one; A[12] = one;
    A[13] = zero; A[14] = zero; A[15] = zero;
    B[0] = xh; B[1] = xl; B[2] = xh;
    B[3] = yh; B[4] = yl; B[5] = yh;
    B[6] = zh; B[7] = zl; B[8] = zh;
    B[9] = one; B[10] = one; B[11] = whB; B[12] = wlB;
    B[13] = zero; B[14] = zero; B[15] = zero;
}

// 32x32x16 tile = 64 entries of f16x8. Lane l -> row/col = l&31, k-group
// g = l>>5. Entry index: g*32 + r. A-slot j and B-slot j at the same (g, i)
// position -> products pair under any shared k-bijection.
// Also writes the opaque 64-B zero block for the mfma kernel's C operand.
__global__ __launch_bounds__(256) void prep_kernel(
        const float* __restrict__ pred, const float* __restrict__ target,
        const int* __restrict__ mask,
        f16x8* __restrict__ predA, f16x8* __restrict__ predB,
        f16x8* __restrict__ tgtA, f16x8* __restrict__ tgtB,
        unsigned int* __restrict__ cnt4, float* __restrict__ czero) {
    int idx = blockIdx.x * 256 + threadIdx.x;
    if (idx < 16) czero[idx] = 0.0f;
    bool valid = mask[idx] != 0;

    float px = pred[idx * 3 + 0], py = pred[idx * 3 + 1], pz = pred[idx * 3 + 2];
    float tx = target[idx * 3 + 0], ty = target[idx * 3 + 1], tz = target[idx * 3 + 2];
    if (!valid) { px = py = pz = 0.0f; tx = ty = tz = 0.0f; }

    f16 PA[16], PB[16], TA[16], TB[16];
    mk_slots(px, py, pz, valid, PA, PB);
    mk_slots(tx, ty, tz, valid, TA, TB);

    int b = idx >> 12, kk = idx & 4095;
    int rt = kk >> 5, r = kk & 31;
    size_t base = ((size_t)(b * 128 + rt)) * 64;

    #pragma unroll
    for (int g = 0; g < 2; ++g) {
        int o = g * 8;
        predA[base + g * 32 + r] = (f16x8){PA[o+0],PA[o+1],PA[o+2],PA[o+3],PA[o+4],PA[o+5],PA[o+6],PA[o+7]};
        predB[base + g * 32 + r] = (f16x8){PB[o+0],PB[o+1],PB[o+2],PB[o+3],PB[o+4],PB[o+5],PB[o+6],PB[o+7]};
        tgtA[base + g * 32 + r]  = (f16x8){TA[o+0],TA[o+1],TA[o+2],TA[o+3],TA[o+4],TA[o+5],TA[o+6],TA[o+7]};
        tgtB[base + g * 32 + r]  = (f16x8){TB[o+0],TB[o+1],TB[o+2],TB[o+3],TB[o+4],TB[o+5],TB[o+6],TB[o+7]};
    }

    unsigned long long mb = __ballot(valid);
    if ((threadIdx.x & 63) == 0)
        cnt4[idx >> 6] = (unsigned int)__popcll(mb);
}

// Round-9: R7 base (qt=8, 512 blocks, 256 thr, (256,2), swizzle — best so
// far at 28.3) + ONE change: the inner loop processes qt in PAIRS with two
// explicitly interleaved accumulator tiles d0/d1. Rationale: across R5/R7/
// R8 the mfma kernel was insensitive to traffic (2x), TLP (2-4x), and
// per-load coverage (2x) — but MFMA-busy always equals the ~7 us pipe
// floor (R2 PMC: 14% x 43.5). The invariant is the codegen: the frugal
// allocator (40 VGPR at cap 128) keeps ONE d tile and reuses it, creating
// a WAR chain MFMA -> full result latency -> 8 min3 -> next MFMA (~120 cyc
// per 32-cyc MFMA), stalling all waves in phase (convoy). Interleaving two
// independent d tiles in source order forces two live accumulators: d1's
// MFMA executes while d0's min3s drain, and vice versa. +16 VGPR (~56-72
// total) << the 256 cap at (256,2) -> no clamp-spill risk (R4/R6 failures
// needed cap 64). Bitwise: each qt's min3 chain keeps its exact operand
// order; chains are independent; interleaving changes nothing numerically.
__global__ __launch_bounds__(256, 2) void chamfer_mfma_kernel(
        const f16x8* __restrict__ predA, const f16x8* __restrict__ predB,
        const f16x8* __restrict__ tgtA, const f16x8* __restrict__ tgtB,
        const float* __restrict__ czero, float* __restrict__ psum) {
    int bid = blockIdx.x;
    int lin = (bid & 7) * 64 + (bid >> 3);    // XCD-contiguous logical id
    int qg8 = lin & 15; lin >>= 4;            // qg8(16) fastest, b(16), dir(2)
    int b   = lin & 15; lin >>= 4;
    int dir = lin;                            // 0: queries=pred, refs=target
    int j0 = dir * 512 + b * 32 + qg8 * 2;    // old logical psum slots
    int j1 = j0 + 1;

    const f16x8* __restrict__ Apack = dir ? predA : tgtA;  // refs
    const f16x8* __restrict__ Bpack = dir ? tgtB  : predB; // queries

    int tid = threadIdx.x;
    int w = tid >> 6, l = tid & 63;

    __shared__ float comb[4][8][64];

    f16x8 bq[8];
    #pragma unroll
    for (int qt = 0; qt < 8; ++qt)
        bq[qt] = Bpack[((size_t)(b * 128 + qg8 * 8 + qt)) * 64 + l];

    // opaque zero C-operand (value IS zero; provenance hidden from compiler)
    f32x16 cz = *(const f32x16*)czero;

    float qA[8], qB[8];
    #pragma unroll
    for (int qt = 0; qt < 8; ++qt) { qA[qt] = QMIN0; qB[qt] = QMIN0; }

    size_t abase = ((size_t)(b * 128)) * 64 + (size_t)w * 64 + l;
    #pragma unroll 4
    for (int t = 0; t < 32; ++t) {
        f16x8 a = Apack[abase + (size_t)t * 256];
        #pragma unroll
        for (int qp = 0; qp < 4; ++qp) {
            int q0 = 2 * qp, q1 = 2 * qp + 1;
            f32x16 d0 = __builtin_amdgcn_mfma_f32_32x32x16_f16(a, bq[q0], cz, 0, 0, 0);
            f32x16 d1 = __builtin_amdgcn_mfma_f32_32x32x16_f16(a, bq[q1], cz, 0, 0, 0);
            #pragma unroll
            for (int i = 0; i < 4; ++i) {
                qA[q0] = fminf(fminf(qA[q0], d0[4 * i + 0]), d0[4 * i + 1]);  // -> v_min3
                qB[q0] = fminf(fminf(qB[q0], d0[4 * i + 2]), d0[4 * i + 3]);  // -> v_min3
                qA[q1] = fminf(fminf(qA[q1], d1[4 * i + 0]), d1[4 * i + 1]);  // -> v_min3
                qB[q1] = fminf(fminf(qB[q1], d1[4 * i + 2]), d1[4 * i + 3]);  // -> v_min3
            }
        }
    }

    #pragma unroll
    for (int qt = 0; qt < 8; ++qt) comb[w][qt][l] = fminf(qA[qt], qB[qt]);
    __syncthreads();

    // Two independent reductions, each the EXACT old-block computation.
    float c0 = 0.0f, c1 = 0.0f;
    if (tid < 128) {
        int qt = tid >> 5, c = tid & 31;
        float m0 = QMIN0, m1 = QMIN0;
        #pragma unroll
        for (int ww = 0; ww < 4; ++ww)
            #pragma unroll
            for (int h = 0; h < 2; ++h) {
                m0 = fminf(m0, comb[ww][qt][h * 32 + c]);
                m1 = fminf(m1, comb[ww][qt + 4][h * 32 + c]);
            }
        // m < -1e4 marks an invalid query (w_q = -WBIG); contributes 0
        c0 = (m0 < -1e4f) ? 0.0f : sqrtf(fmaxf(m0, 1e-12f));
        c1 = (m1 < -1e4f) ? 0.0f : sqrtf(fmaxf(m1, 1e-12f));
    }
    for (int off = 32; off; off >>= 1) {
        c0 += __shfl_down(c0, off, 64);
        c1 += __shfl_down(c1, off, 64);
    }
    __shared__ float ps0[4], ps1[4];
    if ((tid & 63) == 0) { ps0[tid >> 6] = c0; ps1[tid >> 6] = c1; }
    __syncthreads();
    if (tid == 0) {
        psum[j0] = ps0[0] + ps0[1] + ps0[2] + ps0[3];
        psum[j1] = ps1[0] + ps1[1] + ps1[2] + ps1[3];
    }
}

__global__ __launch_bounds__(256) void final_kernel(
        const unsigned int* __restrict__ cnt4, const float* __restrict__ psum,
        float* __restrict__ out) {
    int t = threadIdx.x;
    unsigned int c = 0;
    float s = 0.0f;
    #pragma unroll
    for (int i = 0; i < 4; ++i) {
        c += cnt4[t + 256 * i];
        s += psum[t + 256 * i];
    }
    for (int off = 32; off; off >>= 1) {
        c += __shfl_down(c, off, 64);
        s += __shfl_down(s, off, 64);
    }
    __shared__ unsigned int cs[4];
    __shared__ float ss[4];
    if ((t & 63) == 0) { cs[t >> 6] = c; ss[t >> 6] = s; }
    __syncthreads();
    if (t == 0) {
        unsigned int C = cs[0] + cs[1] + cs[2] + cs[3];
        float S = ss[0] + ss[1] + ss[2] + ss[3];
        out[0] = S * 0.5f / ((float)C + 1e-8f);
    }
}

extern "C" void kernel_launch(void* const* d_in, const int* in_sizes, int n_in,
                              void* d_out, int out_size, void* d_ws, size_t ws_size,
                              hipStream_t stream) {
    const float* pred = (const float*)d_in[0];
    const float* target = (const float*)d_in[1];
    const int* mask = (const int*)d_in[2];
    float* out = (float*)d_out;

    // ws: [predA 2M | predB 2M | tgtA 2M | tgtB 2M | psum 4K | cnt4 4K | czero 64B]
    char* ws = (char*)d_ws;
    size_t off = 0;
    f16x8* predA = (f16x8*)(ws + off); off += FRAG_BYTES;
    f16x8* predB = (f16x8*)(ws + off); off += FRAG_BYTES;
    f16x8* tgtA  = (f16x8*)(ws + off); off += FRAG_BYTES;
    f16x8* tgtB  = (f16x8*)(ws + off); off += FRAG_BYTES;
    float* psum = (float*)(ws + off); off += NPSUM * sizeof(float);
    unsigned int* cnt4 = (unsigned int*)(ws + off); off += 1024 * sizeof(unsigned int);
    float* czero = (float*)(ws + off);

    prep_kernel<<<NPTS / 256, 256, 0, stream>>>(
        pred, target, mask, predA, predB, tgtA, tgtB, cnt4, czero);
    chamfer_mfma_kernel<<<MGRID, 256, 0, stream>>>(
        predA, predB, tgtA, tgtB, czero, psum);
    final_kernel<<<1, 256, 0, stream>>>(cnt4, psum, out);
}